// Round 4
// baseline (261.106 us; speedup 1.0000x reference)
//
#include <hip/hip_runtime.h>
#include <stdint.h>

#define BB 128
#define NN 32768
#define CI 6
#define TOPK 400
#define KEEPK 200
#define SORTN 512
#define NT 1024
#define KPT 32   // keys per thread in kernel B = NN / NT

// ---------------- Kernel A: masked score keys (LDS-staged, coalesced) ------
// key = float bits of score if score > 0.5 else 0 (positive floats: bit
// pattern is order-isomorphic to value). Full GPU: 4096 blocks.
__global__ __launch_bounds__(256) void key_kernel(
        const float* __restrict__ pred, uint32_t* __restrict__ keys) {
    __shared__ float tile[6144];                       // 1024 rows x 6 floats
    const int tid = threadIdx.x;
    const size_t rbase = (size_t)blockIdx.x * 1024;
    const float4* src = reinterpret_cast<const float4*>(pred + rbase * CI);
#pragma unroll
    for (int r = 0; r < 6; r++)
        reinterpret_cast<float4*>(tile)[tid + 256 * r] = src[tid + 256 * r];
    __syncthreads();
    uint32_t* kout = keys + rbase;
#pragma unroll
    for (int r = 0; r < 4; r++) {
        int row = tid + 256 * r;
        float2 c = *reinterpret_cast<const float2*>(&tile[6 * row + 4]);
        float s = fmaxf(c.x, c.y);
        kout[row] = (s > 0.5f) ? __float_as_uint(s) : 0u;
    }
}

// ---- suffix-select helper: find bucket where count-from-top crosses tgt ----
// hist filled + __syncthreads'd by caller. Returns bucket in *sh_bucket
// (0xFFFFFFFF if total < tgt), count strictly above it in *sh_above.
__device__ __forceinline__ void find_cross(
        unsigned int (*hist)[8192], unsigned int tgt,
        int tid, int lane, int wid, unsigned int* wavetot,
        unsigned int* sh_bucket, unsigned int* sh_above) {
    if (tid == 0) { *sh_bucket = 0xFFFFFFFFu; *sh_above = 0u; }
    unsigned int h[8], s = 0;
    const int base = tid * 8;
#pragma unroll
    for (int j = 0; j < 8; j++) { h[j] = hist[0][base + j] + hist[1][base + j]; s += h[j]; }
    unsigned int suf = s;                      // wave inclusive suffix sum
#pragma unroll
    for (int off = 1; off < 64; off <<= 1) {
        unsigned int v = __shfl_down(suf, off);
        if (lane + off < 64) suf += v;
    }
    if (lane == 0) wavetot[wid] = suf;
    __syncthreads();
    if (tid < 16) {                            // exclusive suffix over waves
        unsigned int wv = wavetot[tid], ws = wv;
#pragma unroll
        for (int off = 1; off < 16; off <<= 1) {
            unsigned int v = __shfl_down(ws, off);
            if (tid + off < 16) ws += v;
        }
        wavetot[tid] = ws - wv;
    }
    __syncthreads();
    unsigned int acc = wavetot[wid] + (suf - s);   // strictly above my chunk
#pragma unroll
    for (int j = 7; j >= 0; j--) {                 // high bucket -> low
        if (acc < tgt && acc + h[j] >= tgt) {
            *sh_bucket = (unsigned int)(base + j); *sh_above = acc;
        }
        acc += h[j];
    }
    __syncthreads();
}

// ---------------- Kernel B: per-image select + NMS + output ----------------
__global__ __launch_bounds__(NT) void select_kernel(
        const float* __restrict__ pred, const float* __restrict__ priors,
        const uint32_t* __restrict__ keys, float* __restrict__ out) {
    const int b = blockIdx.x;
    const int tid = threadIdx.x;
    const int lane = tid & 63;
    const int wid = tid >> 6;
    const float* img = pred + (size_t)b * (NN * CI);
    float* oimg = out + (size_t)b * KEEPK * 6;

    __shared__ unsigned int hist[2][8192];
    __shared__ unsigned int wavetot[16];
    __shared__ unsigned int sh_bucket, sh_above, ccount;
    __shared__ unsigned long long cbuf[SORTN];
    __shared__ float4 cbox[TOPK];
    __shared__ float car[TOPK], csc[TOPK];
    __shared__ int clab[TOPK];
    __shared__ unsigned long long supm[TOPK * 7 + 8];
    __shared__ unsigned long long keepw[8];

    for (int i = tid; i < KEEPK * 6; i += NT) oimg[i] = 0.0f;

    // ---- load this image's keys into registers (coalesced, L2/L3-hot)
    const uint32_t* kimg = keys + (size_t)b * NN;
    uint32_t kreg[KPT];
#pragma unroll
    for (int u = 0; u < KPT; u++) kreg[u] = kimg[tid + (u << 10)];

    // ---- level-0: 8192-bucket histogram on bits 31:19
    const int hc = wid & 1;
    for (int i = tid; i < 16384; i += NT) ((unsigned int*)hist)[i] = 0;
    __syncthreads();
#pragma unroll
    for (int u = 0; u < KPT; u++) {
        uint32_t key = kreg[u];
        if (key != 0u) atomicAdd(&hist[hc][key >> 19], 1u);
    }
    __syncthreads();
    unsigned int tgt = TOPK;
    find_cross(hist, tgt, tid, lane, wid, wavetot, &sh_bucket, &sh_above);
    unsigned int beta = sh_bucket, above0 = sh_above;
    __syncthreads();

    uint32_t T;
    if (beta == 0xFFFFFFFFu) {
        T = 1u;                                // fewer than 400 conf-positive
    } else {
        tgt -= above0;
        // ---- level-1: refine within bucket beta on bits 18:6
        for (int i = tid; i < 16384; i += NT) ((unsigned int*)hist)[i] = 0;
        __syncthreads();
#pragma unroll
        for (int u = 0; u < KPT; u++) {
            uint32_t key = kreg[u];
            if ((key >> 19) == beta) atomicAdd(&hist[hc][(key >> 6) & 0x1FFFu], 1u);
        }
        __syncthreads();
        find_cross(hist, tgt, tid, lane, wid, wavetot, &sh_bucket, &sh_above);
        unsigned int gamma = sh_bucket;        // guaranteed found
        __syncthreads();
        T = (beta << 19) | (gamma << 6);
        if (T == 0u) T = 1u;                   // keep zero-keys excluded
    }

    // ---- gather composites (key, ~idx) for keys >= T
    if (tid == 0) ccount = 0;
    if (tid < SORTN) cbuf[tid] = 0ull;
    if (tid < 8) keepw[tid] = 0ull;
    __syncthreads();
#pragma unroll
    for (int u = 0; u < KPT; u++) {
        uint32_t key = kreg[u];
        if (key >= T) {
            unsigned int p = atomicAdd(&ccount, 1u);
            if (p < SORTN) {
                unsigned int idx = (unsigned int)tid + ((unsigned int)u << 10);
                cbuf[p] = ((unsigned long long)key << 32) |
                          (unsigned long long)(0xFFFFFFFFu - idx);
            }
        }
    }
    __syncthreads();

    // ---- bitonic sort 512 desc => exact top_k order (ties: lower idx first)
    for (int kk = 2; kk <= SORTN; kk <<= 1) {
        for (int j = kk >> 1; j > 0; j >>= 1) {
            if (tid < SORTN) {
                int partner = tid ^ j;
                if (partner > tid) {
                    unsigned long long a = cbuf[tid], c = cbuf[partner];
                    if (((tid & kk) == 0) ? (a < c) : (a > c)) {
                        cbuf[tid] = c; cbuf[partner] = a;
                    }
                }
            }
            __syncthreads();
        }
    }

    // ---- decode candidates (reference float op order; no fma)
    if (tid < TOPK) {
        const int t = tid;
        unsigned long long c = cbuf[t];
        uint32_t key = (uint32_t)(c >> 32);
        uint32_t idx = 0xFFFFFFFFu - (uint32_t)(c & 0xFFFFFFFFull);
        int valid = (key != 0u) && (idx < NN);
        float x1 = 0.f, y1 = 0.f, x2 = 0.f, y2 = 0.f;
        int lab = 0;
        if (valid) {
            const float* p = img + (size_t)idx * CI;
            float l0 = p[0], l1 = p[1], l2 = p[2], l3 = p[3], c0 = p[4], c1 = p[5];
            const float* pr = priors + (size_t)idx * 4;
            float px = pr[0], py = pr[1], pw = pr[2], ph = pr[3];
            float cxv = __fadd_rn(px, __fmul_rn(__fmul_rn(l0, 0.1f), pw));
            float cyv = __fadd_rn(py, __fmul_rn(__fmul_rn(l1, 0.1f), ph));
            float ew = __fmul_rn(pw, expf(__fmul_rn(l2, 0.2f)));
            float eh = __fmul_rn(ph, expf(__fmul_rn(l3, 0.2f)));
            float hw = __fmul_rn(ew, 0.5f);
            float hh = __fmul_rn(eh, 0.5f);
            x1 = __fsub_rn(cxv, hw); y1 = __fsub_rn(cyv, hh);
            x2 = __fadd_rn(cxv, hw); y2 = __fadd_rn(cyv, hh);
            lab = (c1 > c0) ? 1 : 0;
        }
        cbox[t] = make_float4(x1, y1, x2, y2);
        csc[t] = __uint_as_float(key);
        car[t] = __fmul_rn(__fsub_rn(x2, x1), __fsub_rn(y2, y1));
        clab[t] = lab;
        if (valid) atomicOr(&keepw[t >> 6], 1ull << (t & 63));
    }
    __syncthreads();

    // ---- suppression bit-matrix, upper triangle only
    for (int task = tid; task < TOPK * 7; task += NT) {
        int i = task / 7;
        int w4 = task - i * 7;
        int jbase = w4 << 6;
        int jmax = (TOPK - jbase < 64) ? (TOPK - jbase) : 64;
        int j0 = i + 1 - jbase; if (j0 < 0) j0 = 0;
        unsigned long long word = 0ull;
        if (j0 < jmax) {
            float4 bi = cbox[i]; float ai = car[i];
            for (int jj = j0; jj < jmax; jj++) {      // cbox[j]: broadcast reads
                int j = jbase + jj;
                float4 bj = cbox[j]; float aj = car[j];
                float iw = fmaxf(__fsub_rn(fminf(bi.z, bj.z), fmaxf(bi.x, bj.x)), 0.0f);
                float ih = fmaxf(__fsub_rn(fminf(bi.w, bj.w), fmaxf(bi.y, bj.y)), 0.0f);
                float inter = __fmul_rn(iw, ih);
                float denom = __fadd_rn(__fsub_rn(__fadd_rn(ai, aj), inter), 1e-12f);
                float iou = __fdiv_rn(inter, denom);
                if (iou > 0.5f) word |= (1ull << jj);
            }
        }
        supm[i * 7 + w4] = word;
    }
    __syncthreads();

    // ---- sequential resolve in one wave, keep bits in registers
    if (tid < 64) {
        int w = tid & 7;                       // lanes 0-6 own words; rest shadow
        unsigned long long kw = keepw[w];
        unsigned long long nxt = supm[w];
        for (int i = 0; i < TOPK; i++) {
            unsigned long long cur = nxt;
            int ni = (i + 1 < TOPK) ? (i + 1) : i;
            nxt = supm[ni * 7 + w];
            unsigned long long wv = __shfl(kw, i >> 6);
            if ((wv >> (i & 63)) & 1ull) kw &= ~cur;
        }
        if (tid < 7) keepw[tid] = kw;
    }
    __syncthreads();

    // ---- output: kept sorted ascending by (score, position), first 200 rows
    if (tid < TOPK) {
        const int t = tid;
        if ((keepw[t >> 6] >> (t & 63)) & 1ull) {
            float st = csc[t];
            int rank = 0;
            for (int j = 0; j < TOPK; j++) {
                bool kj = (keepw[j >> 6] >> (j & 63)) & 1ull;
                float sj = csc[j];
                if (kj && (sj < st || (sj == st && j < t))) rank++;
            }
            if (rank < KEEPK) {
                float4 bx = cbox[t];
                float* row = oimg + (size_t)rank * 6;
                row[0] = (float)clab[t];
                row[1] = st;
                row[2] = bx.x; row[3] = bx.y; row[4] = bx.z; row[5] = bx.w;
            }
        }
    }
}

extern "C" void kernel_launch(void* const* d_in, const int* in_sizes, int n_in,
                              void* d_out, int out_size, void* d_ws, size_t ws_size,
                              hipStream_t stream) {
    const float* pred = (const float*)d_in[0];     // (128, 32768, 6)
    const float* priors = (const float*)d_in[1];   // (32768, 4)
    float* out = (float*)d_out;                    // (128, 200, 6)
    uint32_t* keys = (uint32_t*)d_ws;              // B*N uint32 = 16.8 MB

    key_kernel<<<(BB * NN) / 1024, 256, 0, stream>>>(pred, keys);
    select_kernel<<<BB, NT, 0, stream>>>(pred, priors, keys, out);
}